// Round 11
// baseline (632.947 us; speedup 1.0000x reference)
//
#include <hip/hip_runtime.h>
#include <hip/hip_cooperative_groups.h>

namespace cg = cooperative_groups;

#define DEVINL __device__ __forceinline__

constexpr int N_NODES = 50000;
constexpr int E_EDGES = 800000;
constexpr int HD      = 128;
constexpr int NG      = 64;
constexpr int OUTC    = 64;
constexpr int NPAR    = 22;
constexpr int PAR_TOTAL = 3*(16384+3*128) + (8192+3*64) + 6*128;  // 59456
constexpr int WT_TOTAL = 3*128*128 + 64*128;     // 57344 fp16
constexpr int NB      = (N_NODES + 1023) / 1024; // 49 buckets
constexpr int EBC     = 2048;
constexpr int NBLKC   = (E_EDGES + EBC - 1) / EBC; // 391
constexpr int BNSLOTS = 16;

typedef _Float16 half8_t __attribute__((ext_vector_type(8)));
typedef _Float16 half4_t __attribute__((ext_vector_type(4)));
typedef float    float4_t __attribute__((ext_vector_type(4)));

DEVINL float bf2f(unsigned short u){
  union { unsigned int i; float f; } v; v.i = ((unsigned int)u) << 16; return v.f;
}
DEVINL float lrelu(float v){ return v > 0.f ? v : 0.2f * v; }

struct PtrTab { const void* p[NPAR]; int off[NPAR + 1]; };

// ---------------- cooperative build: prep + CSR (5 kernels -> 1) ----------------
__global__ __launch_bounds__(256) void k_build(PtrTab tab,
    const unsigned short* __restrict__ x, const int* __restrict__ ei,
    int* __restrict__ flags, float* __restrict__ par,
    const void* __restrict__ W0, const void* __restrict__ W1,
    const void* __restrict__ W2, const void* __restrict__ W3,
    _Float16* __restrict__ wt16,
    int* __restrict__ cntmat,          // [NB][NBLKC] bucket-major
    int* __restrict__ gbase,           // [NB][NBLKC]
    int* __restrict__ csum_g,          // [NB]
    int* __restrict__ cbase,           // [NB+1]
    unsigned int* __restrict__ ebuf2,
    int* __restrict__ offs, int* __restrict__ ssrc){
  cg::grid_group grid = cg::this_grid();
  int t = threadIdx.x, blk = blockIdx.x;

  // local dtype sniff (registers; block 0 publishes for later kernels)
  __shared__ int s_f32, s_i64;
  if (t == 0){ s_f32 = 0; s_i64 = 1; }
  __syncthreads();
  for (int i = t; i < 2048; i += 256){
    float v = bf2f(x[i]);
    if (!(fabsf(v) < 1e4f)) s_f32 = 1;
  }
  for (int i = t; i < 512; i += 256){
    if (ei[2 * i + 1] != 0) s_i64 = 0;
  }
  __syncthreads();
  const int f32 = s_f32, i64 = s_i64;
  if (blk == 0 && t == 0){ flags[0] = i64; flags[1] = f32; }

  // phase 0: param conversion + W transpose (grid-stride; independent)
  for (int i = blk * 256 + t; i < PAR_TOTAL + WT_TOTAL; i += gridDim.x * 256){
    if (i < PAR_TOTAL){
      int k = 0;
      while (tab.off[k + 1] <= i) k++;
      int j = i - tab.off[k];
      par[i] = f32 ? ((const float*)tab.p[k])[j] : bf2f(((const unsigned short*)tab.p[k])[j]);
    } else {
      int w = i - PAR_TOTAL;
      const void* W; int base, Mt;
      if (w < 49152){ int l = w >> 14; base = w & 16383; Mt = 128; W = (l == 0) ? W0 : (l == 1 ? W1 : W2); }
      else { base = w - 49152; Mt = 64; W = W3; }
      int nn = base >> 7, k = base & 127;
      float val = f32 ? ((const float*)W)[(size_t)k * Mt + nn]
                      : bf2f(((const unsigned short*)W)[(size_t)k * Mt + nn]);
      wt16[w] = (_Float16)val;
    }
  }

  // phase 1: count + stash packed edges in registers
  unsigned int my[EBC / 256];
  __shared__ int cnt[NB];
  if (blk < NBLKC){
    if (t < NB) cnt[t] = 0;
    __syncthreads();
    int e0 = blk * EBC;
    #pragma unroll
    for (int j = 0; j < EBC / 256; j++){
      int e = e0 + t + j * 256;
      my[j] = 0xFFFFFFFFu;
      if (e < E_EDGES){
        int s = ei[(size_t)e << i64];
        int d = ei[(size_t)(E_EDGES + e) << i64];
        my[j] = (unsigned int)s | ((unsigned int)d << 16);
        atomicAdd(&cnt[d >> 10], 1);
      }
    }
    __syncthreads();
    if (t < NB) cntmat[t * NBLKC + blk] = cnt[t];
  }
  grid.sync();

  // phase 2: per-bucket exclusive prefix across count-blocks (49 blocks, coalesced)
  __shared__ int vals[NBLKC];
  if (blk < NB){
    for (int k = t; k < NBLKC; k += 256) vals[k] = cntmat[blk * NBLKC + k];
    __syncthreads();
    if (t == 0){
      int run = 0;
      for (int k = 0; k < NBLKC; k++){ int c = vals[k]; vals[k] = run; run += c; }
      csum_g[blk] = run;
    }
    __syncthreads();
    for (int k = t; k < NBLKC; k += 256) gbase[blk * NBLKC + k] = vals[k];
  }
  grid.sync();

  // phase 2b: bucket bases
  if (blk == 0 && t == 0){
    int run = 0;
    for (int b = 0; b < NB; b++){ cbase[b] = run; run += csum_g[b]; }
    cbase[NB] = run;
  }
  grid.sync();

  // phase 3: scatter from register stash into exclusive windows
  __shared__ int cur[NB];
  if (blk < NBLKC){
    if (t < NB) cur[t] = gbase[t * NBLKC + blk] + cbase[t];
    __syncthreads();
    #pragma unroll
    for (int j = 0; j < EBC / 256; j++){
      unsigned int pk = my[j];
      if (pk != 0xFFFFFFFFu){
        int p = atomicAdd(&cur[pk >> 26], 1);
        ebuf2[p] = pk;
      }
    }
  }
  grid.sync();

  // phase 4: per-bucket hist -> scan -> offs, scatter ssrc (49 blocks)
  __shared__ int hist[1024];
  __shared__ int wsum[256];
  if (blk < NB){
    int nbase = blk << 10;
    int s0 = cbase[blk], s1 = cbase[blk + 1];
    for (int i = t; i < 1024; i += 256) hist[i] = 0;
    __syncthreads();
    for (int i = s0 + t; i < s1; i += 256){
      unsigned int pk = ebuf2[i];
      atomicAdd(&hist[(int)(pk >> 16) - nbase], 1);
    }
    __syncthreads();
    int base4 = t * 4;
    int v0 = hist[base4], v1 = hist[base4 + 1], v2 = hist[base4 + 2], v3 = hist[base4 + 3];
    int s = v0 + v1 + v2 + v3;
    wsum[t] = s; __syncthreads();
    for (int off = 1; off < 256; off <<= 1){
      int x2 = (t >= off) ? wsum[t - off] : 0;
      __syncthreads();
      wsum[t] += x2;
      __syncthreads();
    }
    int run = s0 + wsum[t] - s;
    int node = nbase + base4;
    if (node < N_NODES) offs[node] = run;  hist[base4] = run;  run += v0;
    if (node + 1 < N_NODES) offs[node + 1] = run;  hist[base4 + 1] = run;  run += v1;
    if (node + 2 < N_NODES) offs[node + 2] = run;  hist[base4 + 2] = run;  run += v2;
    if (node + 3 < N_NODES) offs[node + 3] = run;  hist[base4 + 3] = run;
    if (blk == NB - 1 && t == 255) offs[N_NODES] = s1;
    __syncthreads();
    for (int i = s0 + t; i < s1; i += 256){
      unsigned int pk = ebuf2[i];
      int p = atomicAdd(&hist[(int)(pk >> 16) - nbase], 1);
      ssrc[p] = (int)(pk & 0xFFFFu);
    }
  }
}

// ---------------- fused MFMA GEMM ----------------
template<int MT, bool FIRST>
__global__ __launch_bounds__(256) void k_gemm(
    const void* __restrict__ Ain, const int* __restrict__ flags,
    const float* __restrict__ bnslots,
    const float* __restrict__ g, const float* __restrict__ be,
    const _Float16* __restrict__ Wt16,
    const float* __restrict__ a_s, const float* __restrict__ a_d,
    _Float16* __restrict__ h16, float* __restrict__ als, float* __restrict__ ald,
    int n){
  __shared__ _Float16 AhL[64 * 136];
  __shared__ _Float16 WtL[MT * 72];
  __shared__ float scale[128], shift[128];
  const int t = threadIdx.x;
  const int rowBase = blockIdx.x * 64;
  if (!FIRST){
    if (t < 128){
      float s = 0.f, q = 0.f;
      #pragma unroll
      for (int sl = 0; sl < BNSLOTS; sl++){
        s += bnslots[sl * 256 + t];
        q += bnslots[sl * 256 + 128 + t];
      }
      float inv_n = 1.f / (float)n;
      float mu = s * inv_n;
      float var = q * inv_n - mu * mu;
      float sc = g[t] * rsqrtf(var + 1e-5f);
      scale[t] = sc; shift[t] = be[t] - mu * sc;
    }
    __syncthreads();
  }
  for (int f = t; f < 64 * 16; f += 256){
    int r = f >> 4, c8 = (f & 15) << 3;
    int row = rowBase + r;
    float v[8];
    if (row < n){
      if (FIRST){
        if (flags[1]){
          float4 x0 = *(const float4*)((const float*)Ain + (size_t)row * 128 + c8);
          float4 x1 = *(const float4*)((const float*)Ain + (size_t)row * 128 + c8 + 4);
          v[0]=x0.x; v[1]=x0.y; v[2]=x0.z; v[3]=x0.w;
          v[4]=x1.x; v[5]=x1.y; v[6]=x1.z; v[7]=x1.w;
        } else {
          const unsigned short* xp = (const unsigned short*)Ain + (size_t)row * 128 + c8;
          ushort4 u0 = *(const ushort4*)xp; ushort4 u1 = *(const ushort4*)(xp + 4);
          v[0]=bf2f(u0.x); v[1]=bf2f(u0.y); v[2]=bf2f(u0.z); v[3]=bf2f(u0.w);
          v[4]=bf2f(u1.x); v[5]=bf2f(u1.y); v[6]=bf2f(u1.z); v[7]=bf2f(u1.w);
        }
      } else {
        half8_t a8 = *(const half8_t*)((const _Float16*)Ain + (size_t)row * 128 + c8);
        #pragma unroll
        for (int j = 0; j < 8; j++){
          float xv = (float)a8[j] * scale[c8 + j] + shift[c8 + j];
          v[j] = xv > 0.f ? xv : (__expf(xv) - 1.f);
        }
      }
    } else {
      #pragma unroll
      for (int j = 0; j < 8; j++) v[j] = 0.f;
    }
    half8_t h;
    #pragma unroll
    for (int j = 0; j < 8; j++) h[j] = (_Float16)v[j];
    *(half8_t*)&AhL[r * 136 + c8] = h;
  }
  const int lane = t & 63;
  const int m = lane & 15, quad = lane >> 4;
  const int band = (t >> 6) * 16;
  float4_t acc[MT / 16];
  #pragma unroll
  for (int ct = 0; ct < MT / 16; ct++) acc[ct] = (float4_t){0.f, 0.f, 0.f, 0.f};
  #pragma unroll
  for (int kh = 0; kh < 2; kh++){
    __syncthreads();
    for (int f = t; f < MT * 8; f += 256){
      int nn = f >> 3, c8 = (f & 7) << 3;
      *(half8_t*)&WtL[nn * 72 + c8] = *(const half8_t*)&Wt16[nn * 128 + kh * 64 + c8];
    }
    __syncthreads();
    half8_t a0 = *(half8_t*)&AhL[(band + m) * 136 + kh * 64 + quad * 8];
    half8_t a1 = *(half8_t*)&AhL[(band + m) * 136 + kh * 64 + 32 + quad * 8];
    #pragma unroll
    for (int ct = 0; ct < MT / 16; ct++){
      half8_t b0 = *(half8_t*)&WtL[(ct * 16 + m) * 72 + quad * 8];
      half8_t b1 = *(half8_t*)&WtL[(ct * 16 + m) * 72 + 32 + quad * 8];
      acc[ct] = __builtin_amdgcn_mfma_f32_16x16x32_f16(a0, b0, acc[ct], 0, 0, 0);
      acc[ct] = __builtin_amdgcn_mfma_f32_16x16x32_f16(a1, b1, acc[ct], 0, 0, 0);
    }
  }
  __syncthreads();
  #pragma unroll
  for (int ct = 0; ct < MT / 16; ct++)
    #pragma unroll
    for (int rg = 0; rg < 4; rg++)
      AhL[(band + quad * 4 + rg) * 136 + ct * 16 + m] = (_Float16)acc[ct][rg];
  __syncthreads();
  int r = t >> 2, q = t & 3;
  int row = rowBase + r;
  if (MT == 128){
    if (row < n){
      half8_t h0 = *(half8_t*)&AhL[r * 136 + q * 32];
      half8_t h1 = *(half8_t*)&AhL[r * 136 + q * 32 + 8];
      half8_t h2 = *(half8_t*)&AhL[r * 136 + q * 32 + 16];
      half8_t h3 = *(half8_t*)&AhL[r * 136 + q * 32 + 24];
      float pas = 0.f, pad = 0.f;
      #pragma unroll
      for (int j = 0; j < 8; j++){
        pas += (float)h0[j] * a_s[q * 32 + j]      + (float)h1[j] * a_s[q * 32 + 8 + j]
             + (float)h2[j] * a_s[q * 32 + 16 + j] + (float)h3[j] * a_s[q * 32 + 24 + j];
        pad += (float)h0[j] * a_d[q * 32 + j]      + (float)h1[j] * a_d[q * 32 + 8 + j]
             + (float)h2[j] * a_d[q * 32 + 16 + j] + (float)h3[j] * a_d[q * 32 + 24 + j];
      }
      als[(size_t)row * 4 + q] = pas;
      ald[(size_t)row * 4 + q] = pad;
      _Float16* hp = h16 + (size_t)row * 128 + q * 32;
      *(half8_t*)hp = h0; *(half8_t*)(hp + 8) = h1;
      *(half8_t*)(hp + 16) = h2; *(half8_t*)(hp + 24) = h3;
    }
  } else {
    half8_t h0 = *(half8_t*)&AhL[r * 136 + q * 16];
    half8_t h1 = *(half8_t*)&AhL[r * 136 + q * 16 + 8];
    float pas = 0.f, pad = 0.f;
    #pragma unroll
    for (int j = 0; j < 8; j++){
      pas += (float)h0[j] * a_s[q * 16 + j] + (float)h1[j] * a_s[q * 16 + 8 + j];
      pad += (float)h0[j] * a_d[q * 16 + j] + (float)h1[j] * a_d[q * 16 + 8 + j];
    }
    pas += __shfl_xor(pas, 1); pas += __shfl_xor(pas, 2);
    pad += __shfl_xor(pad, 1); pad += __shfl_xor(pad, 2);
    if (row < n){
      _Float16* hp = h16 + (size_t)row * 64 + q * 16;
      *(half8_t*)hp = h0; *(half8_t*)(hp + 8) = h1;
      if (q == 0){ als[row] = pas; ald[row] = pad; }
    }
  }
}

// ---------------- per-node GAT attention + aggregation (fused epilogues) ----------------
template<int H, int C, int MODE>
__global__ __launch_bounds__(256) void k_attn(const _Float16* __restrict__ h16,
                      const float* __restrict__ als, const float* __restrict__ ald,
                      const int* __restrict__ offs, const int* __restrict__ ssrc,
                      const float* __restrict__ bias,
                      _Float16* __restrict__ a16out, float* __restrict__ bnout,
                      const int* __restrict__ bids, const int* __restrict__ flags,
                      float* __restrict__ psum, int* __restrict__ gcnt, int n){
  constexpr int HC = H * C;
  constexpr int CPL = HC / 16;                 // 8 (4x32) or 4 (1x64)
  int t = threadIdx.x;
  int nib  = t >> 4;
  int node = blockIdx.x * 16 + nib;
  int sub  = t & 15;
  int c0   = sub * CPL;
  int head = c0 / C;

  float ald_h = ald[(size_t)node * H + head];
  float acc[CPL];
  float ssum;
  {
    float w = __expf(lrelu(als[(size_t)node * H + head] + ald_h));
    ssum = w;
    const _Float16* hp = h16 + (size_t)node * HC + c0;
    #pragma unroll
    for (int i = 0; i < CPL; i++) acc[i] = w * (float)hp[i];
  }
  int beg = offs[node];
  int deg = offs[node + 1] - beg;
  int j = 0;
  for (; j + 8 <= deg; j += 8){
    int ss[8]; float al[8]; float w[8];
    #pragma unroll
    for (int u = 0; u < 8; u++) ss[u] = ssrc[beg + j + u];
    #pragma unroll
    for (int u = 0; u < 8; u++) al[u] = als[(size_t)ss[u] * H + head];
    if constexpr (CPL == 8){
      half8_t v[8];
      #pragma unroll
      for (int u = 0; u < 8; u++) v[u] = *(const half8_t*)(h16 + (size_t)ss[u] * HC + c0);
      #pragma unroll
      for (int u = 0; u < 8; u++){ w[u] = __expf(lrelu(al[u] + ald_h)); ssum += w[u]; }
      #pragma unroll
      for (int i = 0; i < 8; i++){
        float a = 0.f;
        #pragma unroll
        for (int u = 0; u < 8; u++) a += w[u] * (float)v[u][i];
        acc[i] += a;
      }
    } else {
      half4_t v[8];
      #pragma unroll
      for (int u = 0; u < 8; u++) v[u] = *(const half4_t*)(h16 + (size_t)ss[u] * HC + c0);
      #pragma unroll
      for (int u = 0; u < 8; u++){ w[u] = __expf(lrelu(al[u] + ald_h)); ssum += w[u]; }
      #pragma unroll
      for (int i = 0; i < 4; i++){
        float a = 0.f;
        #pragma unroll
        for (int u = 0; u < 8; u++) a += w[u] * (float)v[u][i];
        acc[i] += a;
      }
    }
  }
  for (; j + 4 <= deg; j += 4){
    int s0 = ssrc[beg + j], s1 = ssrc[beg + j + 1];
    int s2 = ssrc[beg + j + 2], s3 = ssrc[beg + j + 3];
    float al0 = als[(size_t)s0 * H + head], al1 = als[(size_t)s1 * H + head];
    float al2 = als[(size_t)s2 * H + head], al3 = als[(size_t)s3 * H + head];
    float w0 = __expf(lrelu(al0 + ald_h)), w1 = __expf(lrelu(al1 + ald_h));
    float w2 = __expf(lrelu(al2 + ald_h)), w3 = __expf(lrelu(al3 + ald_h));
    ssum += (w0 + w1) + (w2 + w3);
    if constexpr (CPL == 8){
      half8_t v0 = *(const half8_t*)(h16 + (size_t)s0 * HC + c0);
      half8_t v1 = *(const half8_t*)(h16 + (size_t)s1 * HC + c0);
      half8_t v2 = *(const half8_t*)(h16 + (size_t)s2 * HC + c0);
      half8_t v3 = *(const half8_t*)(h16 + (size_t)s3 * HC + c0);
      #pragma unroll
      for (int i = 0; i < 8; i++)
        acc[i] += w0 * (float)v0[i] + w1 * (float)v1[i]
                + w2 * (float)v2[i] + w3 * (float)v3[i];
    } else {
      half4_t v0 = *(const half4_t*)(h16 + (size_t)s0 * HC + c0);
      half4_t v1 = *(const half4_t*)(h16 + (size_t)s1 * HC + c0);
      half4_t v2 = *(const half4_t*)(h16 + (size_t)s2 * HC + c0);
      half4_t v3 = *(const half4_t*)(h16 + (size_t)s3 * HC + c0);
      #pragma unroll
      for (int i = 0; i < 4; i++)
        acc[i] += w0 * (float)v0[i] + w1 * (float)v1[i]
                + w2 * (float)v2[i] + w3 * (float)v3[i];
    }
  }
  for (; j < deg; j++){
    int s0 = ssrc[beg + j];
    float w0 = __expf(lrelu(als[(size_t)s0 * H + head] + ald_h));
    ssum += w0;
    const _Float16* hp = h16 + (size_t)s0 * HC + c0;
    #pragma unroll
    for (int i = 0; i < CPL; i++) acc[i] += w0 * (float)hp[i];
  }
  float inv_s = 1.f / ssum;
  float v[CPL];
  #pragma unroll
  for (int i = 0; i < CPL; i++) v[i] = acc[i] * inv_s + bias[c0 + i];

  if constexpr (MODE == 0){
    _Float16* op = a16out + (size_t)node * HC + c0;
    half8_t o;
    #pragma unroll
    for (int i = 0; i < CPL; i++) o[i] = (_Float16)v[i];
    *(half8_t*)op = o;
    __shared__ float red[16][132];
    *(float4*)&red[nib][c0]     = make_float4(v[0], v[1], v[2], v[3]);
    *(float4*)&red[nib][c0 + 4] = make_float4(v[4], v[5], v[6], v[7]);
    __syncthreads();
    if (t < 128){
      float s = 0.f, q = 0.f;
      #pragma unroll
      for (int i = 0; i < 16; i++){ float x = red[i][t]; s += x; q += x * x; }
      int slot = blockIdx.x & (BNSLOTS - 1);
      atomicAdd(&bnout[slot * 256 + t], s);
      atomicAdd(&bnout[slot * 256 + 128 + t], q);
    }
  } else {
    __shared__ float pacc[2][64];
    __shared__ int pcnt[2];
    int f = flags[0];
    if (t < 128) pacc[t >> 6][t & 63] = 0.f;
    if (t < 2) pcnt[t] = 0;
    __syncthreads();
    int g  = (int)bids[(size_t)node << f];
    int g0 = (int)bids[(size_t)(blockIdx.x * 16) << f];
    int g1 = (int)bids[(size_t)(blockIdx.x * 16 + 15) << f];
    if (g1 - g0 <= 1){
      int gl = g - g0;
      #pragma unroll
      for (int i = 0; i < 4; i++) atomicAdd(&pacc[gl][c0 + i], v[i]);
      if (sub == 0) atomicAdd(&pcnt[gl], 1);
      __syncthreads();
      if (t < 128){
        int gl2 = t >> 6;
        if (pcnt[gl2] > 0) atomicAdd(&psum[(g0 + gl2) * 64 + (t & 63)], pacc[gl2][t & 63]);
      }
      if (t < 2 && pcnt[t] > 0) atomicAdd(&gcnt[g0 + t], pcnt[t]);
    } else {
      #pragma unroll
      for (int i = 0; i < 4; i++) atomicAdd(&psum[g * 64 + c0 + i], v[i]);
      if (sub == 0) atomicAdd(&gcnt[g], 1);
      __syncthreads();
    }
  }
}

__global__ void k_pool_fin(const float* __restrict__ psum, const int* __restrict__ gcnt,
                           float* __restrict__ out){
  int i = blockIdx.x * 256 + threadIdx.x;
  if (i >= NG * OUTC) return;
  int cnt = gcnt[i >> 6];
  out[i] = psum[i] / (float)(cnt > 1 ? cnt : 1);
}

extern "C" void kernel_launch(void* const* d_in, const int* in_sizes, int n_in,
                              void* d_out, int out_size, void* d_ws, size_t ws_size,
                              hipStream_t stream){
  const unsigned short* x    = (const unsigned short*)d_in[0];
  const int*            ei   = (const int*)d_in[1];
  const int*            bids = (const int*)d_in[2];

  char* p = (char*)d_ws;
  auto carve = [&](size_t bytes) -> void* {
    void* r = (void*)p; p += (bytes + 255) & ~size_t(255); return r;
  };
  _Float16* a16    = (_Float16*)carve((size_t)N_NODES * HD * 2);
  _Float16* h16    = (_Float16*)carve((size_t)N_NODES * HD * 2);
  float*    par    = (float*)carve((size_t)PAR_TOTAL * 4);
  _Float16* wt16   = (_Float16*)carve((size_t)WT_TOTAL * 2);
  float*    als    = (float*)carve((size_t)N_NODES * 4 * 4);
  float*    ald    = (float*)carve((size_t)N_NODES * 4 * 4);
  int*      offs   = (int*)carve((size_t)(N_NODES + 1) * 4);
  int*      ssrc   = (int*)carve((size_t)E_EDGES * 4);
  unsigned int* ebuf2 = (unsigned int*)carve((size_t)E_EDGES * 4);
  int*      cntmat = (int*)carve((size_t)NB * NBLKC * 4);
  int*      gbase  = (int*)carve((size_t)NB * NBLKC * 4);
  int*      csum_g = (int*)carve(256);
  int*      cbase  = (int*)carve((size_t)(NB + 1) * 4);
  int*      flags  = (int*)carve(256);
  // contiguous zero-region (single memset)
  char*     zbeg   = p;
  float*    bnbuf  = (float*)carve((size_t)3 * BNSLOTS * 256 * 4);  // 48 KB
  float*    psum   = (float*)carve(NG * OUTC * 4);
  int*      gcnt   = (int*)carve(256);
  size_t    zlen   = (size_t)(p - zbeg);

  // param table (dict order indices 3..24)
  PtrTab tab;
  int sizes[NPAR];
  for (int l = 0; l < 4; l++){
    int base = 3 + 4 * l;
    tab.p[4 * l + 0] = d_in[base + 0]; sizes[4 * l + 0] = (l < 3) ? 16384 : 8192;
    tab.p[4 * l + 1] = d_in[base + 1]; sizes[4 * l + 1] = (l < 3) ? 128 : 64;
    tab.p[4 * l + 2] = d_in[base + 2]; sizes[4 * l + 2] = (l < 3) ? 128 : 64;
    tab.p[4 * l + 3] = d_in[base + 3]; sizes[4 * l + 3] = (l < 3) ? 128 : 64;
  }
  for (int l = 0; l < 3; l++){
    tab.p[16 + 2 * l]     = d_in[19 + 2 * l];     sizes[16 + 2 * l] = 128;
    tab.p[16 + 2 * l + 1] = d_in[19 + 2 * l + 1]; sizes[16 + 2 * l + 1] = 128;
  }
  tab.off[0] = 0;
  for (int k = 0; k < NPAR; k++) tab.off[k + 1] = tab.off[k] + sizes[k];
  const float* pAS[4], *pAD[4], *pB[4], *pG[3], *pBE[3];
  for (int l = 0; l < 4; l++){
    pAS[l] = par + tab.off[4 * l + 1];
    pAD[l] = par + tab.off[4 * l + 2];
    pB[l]  = par + tab.off[4 * l + 3];
  }
  for (int l = 0; l < 3; l++){
    pG[l]  = par + tab.off[16 + 2 * l];
    pBE[l] = par + tab.off[16 + 2 * l + 1];
  }
  const _Float16* pWT[4] = { wt16, wt16 + 16384, wt16 + 32768, wt16 + 49152 };
  float* bnS[3];
  for (int l = 0; l < 3; l++) bnS[l] = bnbuf + (size_t)l * BNSLOTS * 256;

  hipMemsetAsync(zbeg, 0, zlen, stream);

  // cooperative build: prep + CSR in one kernel
  const void* W0 = d_in[3], *W1 = d_in[7], *W2 = d_in[11], *W3 = d_in[15];
  void* args[] = { (void*)&tab, (void*)&x, (void*)&ei, (void*)&flags, (void*)&par,
                   (void*)&W0, (void*)&W1, (void*)&W2, (void*)&W3, (void*)&wt16,
                   (void*)&cntmat, (void*)&gbase, (void*)&csum_g, (void*)&cbase,
                   (void*)&ebuf2, (void*)&offs, (void*)&ssrc };
  hipLaunchCooperativeKernel((void*)k_build, dim3(NBLKC), dim3(256), args, 0, stream);

  int gemmBlocks = (N_NODES + 63) / 64;
  int attnBlocks = N_NODES / 16;   // 3125, exact

  // layer 0
  k_gemm<128, true><<<gemmBlocks, 256, 0, stream>>>(
      (const void*)x, flags, nullptr, nullptr, nullptr,
      pWT[0], pAS[0], pAD[0], h16, als, ald, N_NODES);
  k_attn<4, 32, 0><<<attnBlocks, 256, 0, stream>>>(h16, als, ald, offs, ssrc, pB[0],
      a16, bnS[0], nullptr, nullptr, nullptr, nullptr, N_NODES);
  // layers 1,2
  for (int l = 1; l < 3; l++){
    k_gemm<128, false><<<gemmBlocks, 256, 0, stream>>>(
        (const void*)a16, flags, bnS[l-1], pG[l-1], pBE[l-1],
        pWT[l], pAS[l], pAD[l], h16, als, ald, N_NODES);
    k_attn<4, 32, 0><<<attnBlocks, 256, 0, stream>>>(h16, als, ald, offs, ssrc, pB[l],
        a16, bnS[l], nullptr, nullptr, nullptr, nullptr, N_NODES);
  }
  // final layer (1 head, 64 ch) + fused pool
  k_gemm<64, false><<<gemmBlocks, 256, 0, stream>>>(
      (const void*)a16, flags, bnS[2], pG[2], pBE[2],
      pWT[3], pAS[3], pAD[3], h16, als, ald, N_NODES);
  k_attn<1, 64, 1><<<attnBlocks, 256, 0, stream>>>(h16, als, ald, offs, ssrc, pB[3],
      nullptr, nullptr, bids, flags, psum, gcnt, N_NODES);

  k_pool_fin<<<16, 256, 0, stream>>>(psum, gcnt, (float*)d_out);
}

// Round 12
// 422.926 us; speedup vs baseline: 1.4966x; 1.4966x over previous
//
#include <hip/hip_runtime.h>

#define DEVINL __device__ __forceinline__

constexpr int N_NODES = 50000;
constexpr int E_EDGES = 800000;
constexpr int HD      = 128;
constexpr int NG      = 64;
constexpr int OUTC    = 64;
constexpr int NPAR    = 22;
constexpr int PAR_TOTAL = 3*(16384+3*128) + (8192+3*64) + 6*128;  // 59456
constexpr int WT_TOTAL = 3*128*128 + 64*128;     // 57344 fp16
constexpr int NB      = (N_NODES + 1023) / 1024; // 49 buckets
constexpr int EBC     = 2048;
constexpr int NBLKC   = (E_EDGES + EBC - 1) / EBC; // 391
constexpr int BNSLOTS = 16;

typedef _Float16 half8_t __attribute__((ext_vector_type(8)));
typedef _Float16 half4_t __attribute__((ext_vector_type(4)));
typedef float    float4_t __attribute__((ext_vector_type(4)));

DEVINL float bf2f(unsigned short u){
  union { unsigned int i; float f; } v; v.i = ((unsigned int)u) << 16; return v.f;
}
DEVINL float lrelu(float v){ return v > 0.f ? v : 0.2f * v; }

// ---------------- param conversion + W transpose + dtype sniff (merged) ----------------
struct PtrTab { const void* p[NPAR]; int off[NPAR + 1]; };

__global__ void k_prep(PtrTab tab, const unsigned short* __restrict__ x,
                       const int* __restrict__ ei, int* __restrict__ flags,
                       float* __restrict__ dst,
                       const void* __restrict__ W0, const void* __restrict__ W1,
                       const void* __restrict__ W2, const void* __restrict__ W3,
                       _Float16* __restrict__ wt16){
  __shared__ int s_f32, s_i64;
  int t = threadIdx.x;
  if (t == 0){ s_f32 = 0; s_i64 = 1; }
  __syncthreads();
  for (int i = t; i < 2048; i += 256){
    float v = bf2f(x[i]);
    if (!(fabsf(v) < 1e4f)) s_f32 = 1;
  }
  for (int i = t; i < 512; i += 256){
    if (ei[2 * i + 1] != 0) s_i64 = 0;
  }
  __syncthreads();
  int f = s_f32;
  if (blockIdx.x == 0 && t == 0){ flags[0] = s_i64; flags[1] = s_f32; }

  int i = blockIdx.x * 256 + t;
  if (i < PAR_TOTAL){
    int k = 0;
    while (tab.off[k + 1] <= i) k++;
    int j = i - tab.off[k];
    dst[i] = f ? ((const float*)tab.p[k])[j] : bf2f(((const unsigned short*)tab.p[k])[j]);
    return;
  }
  int w = i - PAR_TOTAL;
  if (w >= WT_TOTAL) return;
  const void* W; int base, Mt;
  if (w < 49152){ int l = w >> 14; base = w & 16383; Mt = 128; W = (l == 0) ? W0 : (l == 1 ? W1 : W2); }
  else { base = w - 49152; Mt = 64; W = W3; }
  int nn = base >> 7, k = base & 127;
  float val = f ? ((const float*)W)[(size_t)k * Mt + nn]
                : bf2f(((const unsigned short*)W)[(size_t)k * Mt + nn]);
  wt16[w] = (_Float16)val;
}

// ---------------- CSR build: atomic-cursor 4-phase ----------------
// Phase 1: bucket totals (LDS-aggregated, 49 global atomics per block)
__global__ __launch_bounds__(256) void k_count(const int* __restrict__ ei,
                      const int* __restrict__ flags, int* __restrict__ btot){
  __shared__ int cnt[NB];
  int t = threadIdx.x, blk = blockIdx.x;
  if (t < NB) cnt[t] = 0;
  __syncthreads();
  int f = flags[0];
  int e0 = blk * EBC;
  #pragma unroll
  for (int j = 0; j < EBC / 256; j++){
    int e = e0 + t + j * 256;
    if (e < E_EDGES){
      int d = ei[(size_t)(E_EDGES + e) << f];
      atomicAdd(&cnt[d >> 10], 1);
    }
  }
  __syncthreads();
  if (t < NB && cnt[t] > 0) atomicAdd(&btot[t], cnt[t]);
}

// Phase 2: bucket prefix + global cursor init (tiny)
__global__ void k_cbase(const int* __restrict__ btot, int* __restrict__ cbase,
                        int* __restrict__ cursor){
  int t = threadIdx.x;
  __shared__ int cb[NB + 1];
  if (t == 0){
    int run = 0;
    for (int b = 0; b < NB; b++){ cb[b] = run; run += btot[b]; }
    cb[NB] = run;
  }
  __syncthreads();
  if (t <= NB) cbase[t] = cb[t];
  if (t < NB)  cursor[t] = cb[t];
}

// Phase 3: bin+scatter from register stash (window reservation via global cursors)
__global__ __launch_bounds__(256) void k_binscatter(const int* __restrict__ ei,
                      const int* __restrict__ flags, int* __restrict__ cursor,
                      unsigned int* __restrict__ ebuf2){
  __shared__ int cnt[NB];
  __shared__ int cur[NB];
  int t = threadIdx.x, blk = blockIdx.x;
  if (t < NB) cnt[t] = 0;
  __syncthreads();
  int f = flags[0];
  int e0 = blk * EBC;
  unsigned int my[EBC / 256];
  #pragma unroll
  for (int j = 0; j < EBC / 256; j++){
    int e = e0 + t + j * 256;
    my[j] = 0xFFFFFFFFu;
    if (e < E_EDGES){
      int s = ei[(size_t)e << f];
      int d = ei[(size_t)(E_EDGES + e) << f];
      my[j] = (unsigned int)s | ((unsigned int)d << 16);
      atomicAdd(&cnt[d >> 10], 1);
    }
  }
  __syncthreads();
  if (t < NB && cnt[t] > 0) cur[t] = atomicAdd(&cursor[t], cnt[t]);
  __syncthreads();
  #pragma unroll
  for (int j = 0; j < EBC / 256; j++){
    unsigned int pk = my[j];
    if (pk != 0xFFFFFFFFu){
      int p = atomicAdd(&cur[pk >> 26], 1);
      ebuf2[p] = pk;
    }
  }
}

// Phase 4: per-bucket hist -> scan -> offs, scatter ssrc
__global__ __launch_bounds__(256) void k_csrD(const unsigned int* __restrict__ ebuf2,
                      const int* __restrict__ cbase, int* __restrict__ offs,
                      int* __restrict__ ssrc, int n){
  __shared__ int hist[1024];
  __shared__ int wsum[256];
  int t = threadIdx.x, b = blockIdx.x;
  int nbase = b << 10;
  int s0 = cbase[b], s1 = cbase[b + 1];
  for (int i = t; i < 1024; i += 256) hist[i] = 0;
  __syncthreads();
  for (int i = s0 + t; i < s1; i += 256){
    unsigned int pk = ebuf2[i];
    atomicAdd(&hist[(int)(pk >> 16) - nbase], 1);
  }
  __syncthreads();
  int base4 = t * 4;
  int v0 = hist[base4], v1 = hist[base4 + 1], v2 = hist[base4 + 2], v3 = hist[base4 + 3];
  int s = v0 + v1 + v2 + v3;
  wsum[t] = s; __syncthreads();
  for (int off = 1; off < 256; off <<= 1){
    int x2 = (t >= off) ? wsum[t - off] : 0;
    __syncthreads();
    wsum[t] += x2;
    __syncthreads();
  }
  int run = s0 + wsum[t] - s;
  int node = nbase + base4;
  if (node < n) offs[node] = run;  hist[base4] = run;  run += v0;
  if (node + 1 < n) offs[node + 1] = run;  hist[base4 + 1] = run;  run += v1;
  if (node + 2 < n) offs[node + 2] = run;  hist[base4 + 2] = run;  run += v2;
  if (node + 3 < n) offs[node + 3] = run;  hist[base4 + 3] = run;
  if (b == NB - 1 && t == 255) offs[n] = s1;
  __syncthreads();
  for (int i = s0 + t; i < s1; i += 256){
    unsigned int pk = ebuf2[i];
    int p = atomicAdd(&hist[(int)(pk >> 16) - nbase], 1);
    ssrc[p] = (int)(pk & 0xFFFFu);
  }
}

// ---------------- fused MFMA GEMM ----------------
template<int MT, bool FIRST>
__global__ __launch_bounds__(256) void k_gemm(
    const void* __restrict__ Ain, const int* __restrict__ flags,
    const float* __restrict__ bnslots,
    const float* __restrict__ g, const float* __restrict__ be,
    const _Float16* __restrict__ Wt16,
    const float* __restrict__ a_s, const float* __restrict__ a_d,
    _Float16* __restrict__ h16, float* __restrict__ als, float* __restrict__ ald,
    int n){
  __shared__ _Float16 AhL[64 * 136];
  __shared__ _Float16 WtL[MT * 72];
  __shared__ float scale[128], shift[128];
  const int t = threadIdx.x;
  const int rowBase = blockIdx.x * 64;
  if (!FIRST){
    if (t < 128){
      float s = 0.f, q = 0.f;
      #pragma unroll
      for (int sl = 0; sl < BNSLOTS; sl++){
        s += bnslots[sl * 256 + t];
        q += bnslots[sl * 256 + 128 + t];
      }
      float inv_n = 1.f / (float)n;
      float mu = s * inv_n;
      float var = q * inv_n - mu * mu;
      float sc = g[t] * rsqrtf(var + 1e-5f);
      scale[t] = sc; shift[t] = be[t] - mu * sc;
    }
    __syncthreads();
  }
  for (int f = t; f < 64 * 16; f += 256){
    int r = f >> 4, c8 = (f & 15) << 3;
    int row = rowBase + r;
    float v[8];
    if (row < n){
      if (FIRST){
        if (flags[1]){
          float4 x0 = *(const float4*)((const float*)Ain + (size_t)row * 128 + c8);
          float4 x1 = *(const float4*)((const float*)Ain + (size_t)row * 128 + c8 + 4);
          v[0]=x0.x; v[1]=x0.y; v[2]=x0.z; v[3]=x0.w;
          v[4]=x1.x; v[5]=x1.y; v[6]=x1.z; v[7]=x1.w;
        } else {
          const unsigned short* xp = (const unsigned short*)Ain + (size_t)row * 128 + c8;
          ushort4 u0 = *(const ushort4*)xp; ushort4 u1 = *(const ushort4*)(xp + 4);
          v[0]=bf2f(u0.x); v[1]=bf2f(u0.y); v[2]=bf2f(u0.z); v[3]=bf2f(u0.w);
          v[4]=bf2f(u1.x); v[5]=bf2f(u1.y); v[6]=bf2f(u1.z); v[7]=bf2f(u1.w);
        }
      } else {
        half8_t a8 = *(const half8_t*)((const _Float16*)Ain + (size_t)row * 128 + c8);
        #pragma unroll
        for (int j = 0; j < 8; j++){
          float xv = (float)a8[j] * scale[c8 + j] + shift[c8 + j];
          v[j] = xv > 0.f ? xv : (__expf(xv) - 1.f);
        }
      }
    } else {
      #pragma unroll
      for (int j = 0; j < 8; j++) v[j] = 0.f;
    }
    half8_t h;
    #pragma unroll
    for (int j = 0; j < 8; j++) h[j] = (_Float16)v[j];
    *(half8_t*)&AhL[r * 136 + c8] = h;
  }
  const int lane = t & 63;
  const int m = lane & 15, quad = lane >> 4;
  const int band = (t >> 6) * 16;
  float4_t acc[MT / 16];
  #pragma unroll
  for (int ct = 0; ct < MT / 16; ct++) acc[ct] = (float4_t){0.f, 0.f, 0.f, 0.f};
  #pragma unroll
  for (int kh = 0; kh < 2; kh++){
    __syncthreads();
    for (int f = t; f < MT * 8; f += 256){
      int nn = f >> 3, c8 = (f & 7) << 3;
      *(half8_t*)&WtL[nn * 72 + c8] = *(const half8_t*)&Wt16[nn * 128 + kh * 64 + c8];
    }
    __syncthreads();
    half8_t a0 = *(half8_t*)&AhL[(band + m) * 136 + kh * 64 + quad * 8];
    half8_t a1 = *(half8_t*)&AhL[(band + m) * 136 + kh * 64 + 32 + quad * 8];
    #pragma unroll
    for (int ct = 0; ct < MT / 16; ct++){
      half8_t b0 = *(half8_t*)&WtL[(ct * 16 + m) * 72 + quad * 8];
      half8_t b1 = *(half8_t*)&WtL[(ct * 16 + m) * 72 + 32 + quad * 8];
      acc[ct] = __builtin_amdgcn_mfma_f32_16x16x32_f16(a0, b0, acc[ct], 0, 0, 0);
      acc[ct] = __builtin_amdgcn_mfma_f32_16x16x32_f16(a1, b1, acc[ct], 0, 0, 0);
    }
  }
  __syncthreads();
  #pragma unroll
  for (int ct = 0; ct < MT / 16; ct++)
    #pragma unroll
    for (int rg = 0; rg < 4; rg++)
      AhL[(band + quad * 4 + rg) * 136 + ct * 16 + m] = (_Float16)acc[ct][rg];
  __syncthreads();
  int r = t >> 2, q = t & 3;
  int row = rowBase + r;
  if (MT == 128){
    if (row < n){
      half8_t h0 = *(half8_t*)&AhL[r * 136 + q * 32];
      half8_t h1 = *(half8_t*)&AhL[r * 136 + q * 32 + 8];
      half8_t h2 = *(half8_t*)&AhL[r * 136 + q * 32 + 16];
      half8_t h3 = *(half8_t*)&AhL[r * 136 + q * 32 + 24];
      float pas = 0.f, pad = 0.f;
      #pragma unroll
      for (int j = 0; j < 8; j++){
        pas += (float)h0[j] * a_s[q * 32 + j]      + (float)h1[j] * a_s[q * 32 + 8 + j]
             + (float)h2[j] * a_s[q * 32 + 16 + j] + (float)h3[j] * a_s[q * 32 + 24 + j];
        pad += (float)h0[j] * a_d[q * 32 + j]      + (float)h1[j] * a_d[q * 32 + 8 + j]
             + (float)h2[j] * a_d[q * 32 + 16 + j] + (float)h3[j] * a_d[q * 32 + 24 + j];
      }
      als[(size_t)row * 4 + q] = pas;
      ald[(size_t)row * 4 + q] = pad;
      _Float16* hp = h16 + (size_t)row * 128 + q * 32;
      *(half8_t*)hp = h0; *(half8_t*)(hp + 8) = h1;
      *(half8_t*)(hp + 16) = h2; *(half8_t*)(hp + 24) = h3;
    }
  } else {
    half8_t h0 = *(half8_t*)&AhL[r * 136 + q * 16];
    half8_t h1 = *(half8_t*)&AhL[r * 136 + q * 16 + 8];
    float pas = 0.f, pad = 0.f;
    #pragma unroll
    for (int j = 0; j < 8; j++){
      pas += (float)h0[j] * a_s[q * 16 + j] + (float)h1[j] * a_s[q * 16 + 8 + j];
      pad += (float)h0[j] * a_d[q * 16 + j] + (float)h1[j] * a_d[q * 16 + 8 + j];
    }
    pas += __shfl_xor(pas, 1); pas += __shfl_xor(pas, 2);
    pad += __shfl_xor(pad, 1); pad += __shfl_xor(pad, 2);
    if (row < n){
      _Float16* hp = h16 + (size_t)row * 64 + q * 16;
      *(half8_t*)hp = h0; *(half8_t*)(hp + 8) = h1;
      if (q == 0){ als[row] = pas; ald[row] = pad; }
    }
  }
}

// ---------------- per-node GAT attention + aggregation (fused epilogues) ----------------
// 16-lane group per node; per-lane ssum; 8-wide gather unroll.
// MODE 0: fp16 out + BN partial sums into 16 slots. MODE 1: fused mean-pool.
template<int H, int C, int MODE>
__global__ __launch_bounds__(256) void k_attn(const _Float16* __restrict__ h16,
                      const float* __restrict__ als, const float* __restrict__ ald,
                      const int* __restrict__ offs, const int* __restrict__ ssrc,
                      const float* __restrict__ bias,
                      _Float16* __restrict__ a16out, float* __restrict__ bnout,
                      const int* __restrict__ bids, const int* __restrict__ flags,
                      float* __restrict__ psum, int* __restrict__ gcnt, int n){
  constexpr int HC = H * C;
  constexpr int CPL = HC / 16;                 // 8 (4x32) or 4 (1x64)
  int t = threadIdx.x;
  int nib  = t >> 4;
  int node = blockIdx.x * 16 + nib;
  int sub  = t & 15;
  int c0   = sub * CPL;
  int head = c0 / C;

  float ald_h = ald[(size_t)node * H + head];
  float acc[CPL];
  float ssum;
  {
    float w = __expf(lrelu(als[(size_t)node * H + head] + ald_h));
    ssum = w;
    const _Float16* hp = h16 + (size_t)node * HC + c0;
    #pragma unroll
    for (int i = 0; i < CPL; i++) acc[i] = w * (float)hp[i];
  }
  int beg = offs[node];
  int deg = offs[node + 1] - beg;
  int j = 0;
  for (; j + 8 <= deg; j += 8){
    int ss[8]; float al[8]; float w[8];
    #pragma unroll
    for (int u = 0; u < 8; u++) ss[u] = ssrc[beg + j + u];
    #pragma unroll
    for (int u = 0; u < 8; u++) al[u] = als[(size_t)ss[u] * H + head];
    if constexpr (CPL == 8){
      half8_t v[8];
      #pragma unroll
      for (int u = 0; u < 8; u++) v[u] = *(const half8_t*)(h16 + (size_t)ss[u] * HC + c0);
      #pragma unroll
      for (int u = 0; u < 8; u++){ w[u] = __expf(lrelu(al[u] + ald_h)); ssum += w[u]; }
      #pragma unroll
      for (int i = 0; i < 8; i++){
        float a = 0.f;
        #pragma unroll
        for (int u = 0; u < 8; u++) a += w[u] * (float)v[u][i];
        acc[i] += a;
      }
    } else {
      half4_t v[8];
      #pragma unroll
      for (int u = 0; u < 8; u++) v[u] = *(const half4_t*)(h16 + (size_t)ss[u] * HC + c0);
      #pragma unroll
      for (int u = 0; u < 8; u++){ w[u] = __expf(lrelu(al[u] + ald_h)); ssum += w[u]; }
      #pragma unroll
      for (int i = 0; i < 4; i++){
        float a = 0.f;
        #pragma unroll
        for (int u = 0; u < 8; u++) a += w[u] * (float)v[u][i];
        acc[i] += a;
      }
    }
  }
  for (; j + 4 <= deg; j += 4){
    int s0 = ssrc[beg + j], s1 = ssrc[beg + j + 1];
    int s2 = ssrc[beg + j + 2], s3 = ssrc[beg + j + 3];
    float al0 = als[(size_t)s0 * H + head], al1 = als[(size_t)s1 * H + head];
    float al2 = als[(size_t)s2 * H + head], al3 = als[(size_t)s3 * H + head];
    float w0 = __expf(lrelu(al0 + ald_h)), w1 = __expf(lrelu(al1 + ald_h));
    float w2 = __expf(lrelu(al2 + ald_h)), w3 = __expf(lrelu(al3 + ald_h));
    ssum += (w0 + w1) + (w2 + w3);
    if constexpr (CPL == 8){
      half8_t v0 = *(const half8_t*)(h16 + (size_t)s0 * HC + c0);
      half8_t v1 = *(const half8_t*)(h16 + (size_t)s1 * HC + c0);
      half8_t v2 = *(const half8_t*)(h16 + (size_t)s2 * HC + c0);
      half8_t v3 = *(const half8_t*)(h16 + (size_t)s3 * HC + c0);
      #pragma unroll
      for (int i = 0; i < 8; i++)
        acc[i] += w0 * (float)v0[i] + w1 * (float)v1[i]
                + w2 * (float)v2[i] + w3 * (float)v3[i];
    } else {
      half4_t v0 = *(const half4_t*)(h16 + (size_t)s0 * HC + c0);
      half4_t v1 = *(const half4_t*)(h16 + (size_t)s1 * HC + c0);
      half4_t v2 = *(const half4_t*)(h16 + (size_t)s2 * HC + c0);
      half4_t v3 = *(const half4_t*)(h16 + (size_t)s3 * HC + c0);
      #pragma unroll
      for (int i = 0; i < 4; i++)
        acc[i] += w0 * (float)v0[i] + w1 * (float)v1[i]
                + w2 * (float)v2[i] + w3 * (float)v3[i];
    }
  }
  for (; j < deg; j++){
    int s0 = ssrc[beg + j];
    float w0 = __expf(lrelu(als[(size_t)s0 * H + head] + ald_h));
    ssum += w0;
    const _Float16* hp = h16 + (size_t)s0 * HC + c0;
    #pragma unroll
    for (int i = 0; i < CPL; i++) acc[i] += w0 * (float)hp[i];
  }
  float inv_s = 1.f / ssum;
  float v[CPL];
  #pragma unroll
  for (int i = 0; i < CPL; i++) v[i] = acc[i] * inv_s + bias[c0 + i];

  if constexpr (MODE == 0){
    _Float16* op = a16out + (size_t)node * HC + c0;
    half8_t o;
    #pragma unroll
    for (int i = 0; i < CPL; i++) o[i] = (_Float16)v[i];
    *(half8_t*)op = o;
    __shared__ float red[16][132];
    *(float4*)&red[nib][c0]     = make_float4(v[0], v[1], v[2], v[3]);
    *(float4*)&red[nib][c0 + 4] = make_float4(v[4], v[5], v[6], v[7]);
    __syncthreads();
    if (t < 128){
      float s = 0.f, q = 0.f;
      #pragma unroll
      for (int i = 0; i < 16; i++){ float x = red[i][t]; s += x; q += x * x; }
      int slot = blockIdx.x & (BNSLOTS - 1);
      atomicAdd(&bnout[slot * 256 + t], s);
      atomicAdd(&bnout[slot * 256 + 128 + t], q);
    }
  } else {
    __shared__ float pacc[2][64];
    __shared__ int pcnt[2];
    int f = flags[0];
    if (t < 128) pacc[t >> 6][t & 63] = 0.f;
    if (t < 2) pcnt[t] = 0;
    __syncthreads();
    int g  = (int)bids[(size_t)node << f];
    int g0 = (int)bids[(size_t)(blockIdx.x * 16) << f];
    int g1 = (int)bids[(size_t)(blockIdx.x * 16 + 15) << f];
    if (g1 - g0 <= 1){
      int gl = g - g0;
      #pragma unroll
      for (int i = 0; i < 4; i++) atomicAdd(&pacc[gl][c0 + i], v[i]);
      if (sub == 0) atomicAdd(&pcnt[gl], 1);
      __syncthreads();
      if (t < 128){
        int gl2 = t >> 6;
        if (pcnt[gl2] > 0) atomicAdd(&psum[(g0 + gl2) * 64 + (t & 63)], pacc[gl2][t & 63]);
      }
      if (t < 2 && pcnt[t] > 0) atomicAdd(&gcnt[g0 + t], pcnt[t]);
    } else {
      #pragma unroll
      for (int i = 0; i < 4; i++) atomicAdd(&psum[g * 64 + c0 + i], v[i]);
      if (sub == 0) atomicAdd(&gcnt[g], 1);
      __syncthreads();
    }
  }
}

__global__ void k_pool_fin(const float* __restrict__ psum, const int* __restrict__ gcnt,
                           float* __restrict__ out){
  int i = blockIdx.x * 256 + threadIdx.x;
  if (i >= NG * OUTC) return;
  int cnt = gcnt[i >> 6];
  out[i] = psum[i] / (float)(cnt > 1 ? cnt : 1);
}

extern "C" void kernel_launch(void* const* d_in, const int* in_sizes, int n_in,
                              void* d_out, int out_size, void* d_ws, size_t ws_size,
                              hipStream_t stream){
  const unsigned short* x    = (const unsigned short*)d_in[0];
  const int*            ei   = (const int*)d_in[1];
  const int*            bids = (const int*)d_in[2];

  char* p = (char*)d_ws;
  auto carve = [&](size_t bytes) -> void* {
    void* r = (void*)p; p += (bytes + 255) & ~size_t(255); return r;
  };
  _Float16* a16    = (_Float16*)carve((size_t)N_NODES * HD * 2);
  _Float16* h16    = (_Float16*)carve((size_t)N_NODES * HD * 2);
  float*    par    = (float*)carve((size_t)PAR_TOTAL * 4);
  _Float16* wt16   = (_Float16*)carve((size_t)WT_TOTAL * 2);
  float*    als    = (float*)carve((size_t)N_NODES * 4 * 4);
  float*    ald    = (float*)carve((size_t)N_NODES * 4 * 4);
  int*      offs   = (int*)carve((size_t)(N_NODES + 1) * 4);
  int*      ssrc   = (int*)carve((size_t)E_EDGES * 4);
  unsigned int* ebuf2 = (unsigned int*)carve((size_t)E_EDGES * 4);
  int*      cbase  = (int*)carve((size_t)(NB + 1) * 4);
  int*      cursor = (int*)carve(256);
  int*      flags  = (int*)carve(256);
  // contiguous zero-region (single memset)
  char*     zbeg   = p;
  int*      btot   = (int*)carve(256);
  float*    bnbuf  = (float*)carve((size_t)3 * BNSLOTS * 256 * 4);  // 48 KB
  float*    psum   = (float*)carve(NG * OUTC * 4);
  int*      gcnt   = (int*)carve(256);
  size_t    zlen   = (size_t)(p - zbeg);

  // param table (dict order indices 3..24)
  PtrTab tab;
  int sizes[NPAR];
  for (int l = 0; l < 4; l++){
    int base = 3 + 4 * l;
    tab.p[4 * l + 0] = d_in[base + 0]; sizes[4 * l + 0] = (l < 3) ? 16384 : 8192;
    tab.p[4 * l + 1] = d_in[base + 1]; sizes[4 * l + 1] = (l < 3) ? 128 : 64;
    tab.p[4 * l + 2] = d_in[base + 2]; sizes[4 * l + 2] = (l < 3) ? 128 : 64;
    tab.p[4 * l + 3] = d_in[base + 3]; sizes[4 * l + 3] = (l < 3) ? 128 : 64;
  }
  for (int l = 0; l < 3; l++){
    tab.p[16 + 2 * l]     = d_in[19 + 2 * l];     sizes[16 + 2 * l] = 128;
    tab.p[16 + 2 * l + 1] = d_in[19 + 2 * l + 1]; sizes[16 + 2 * l + 1] = 128;
  }
  tab.off[0] = 0;
  for (int k = 0; k < NPAR; k++) tab.off[k + 1] = tab.off[k] + sizes[k];
  const float* pAS[4], *pAD[4], *pB[4], *pG[3], *pBE[3];
  for (int l = 0; l < 4; l++){
    pAS[l] = par + tab.off[4 * l + 1];
    pAD[l] = par + tab.off[4 * l + 2];
    pB[l]  = par + tab.off[4 * l + 3];
  }
  for (int l = 0; l < 3; l++){
    pG[l]  = par + tab.off[16 + 2 * l];
    pBE[l] = par + tab.off[16 + 2 * l + 1];
  }
  const _Float16* pWT[4] = { wt16, wt16 + 16384, wt16 + 32768, wt16 + 49152 };
  float* bnS[3];
  for (int l = 0; l < 3; l++) bnS[l] = bnbuf + (size_t)l * BNSLOTS * 256;

  hipMemsetAsync(zbeg, 0, zlen, stream);

  // prep (self-sniffing dtype flags)
  k_prep<<<(PAR_TOTAL + WT_TOTAL + 255) / 256, 256, 0, stream>>>(
      tab, x, ei, flags, par, d_in[3], d_in[7], d_in[11], d_in[15], wt16);

  // CSR build (atomic-cursor 4-phase)
  k_count<<<NBLKC, 256, 0, stream>>>(ei, flags, btot);
  k_cbase<<<1, 64, 0, stream>>>(btot, cbase, cursor);
  k_binscatter<<<NBLKC, 256, 0, stream>>>(ei, flags, cursor, ebuf2);
  k_csrD<<<NB, 256, 0, stream>>>(ebuf2, cbase, offs, ssrc, N_NODES);

  int gemmBlocks = (N_NODES + 63) / 64;
  int attnBlocks = N_NODES / 16;   // 3125, exact

  // layer 0
  k_gemm<128, true><<<gemmBlocks, 256, 0, stream>>>(
      (const void*)x, flags, nullptr, nullptr, nullptr,
      pWT[0], pAS[0], pAD[0], h16, als, ald, N_NODES);
  k_attn<4, 32, 0><<<attnBlocks, 256, 0, stream>>>(h16, als, ald, offs, ssrc, pB[0],
      a16, bnS[0], nullptr, nullptr, nullptr, nullptr, N_NODES);
  // layers 1,2
  for (int l = 1; l < 3; l++){
    k_gemm<128, false><<<gemmBlocks, 256, 0, stream>>>(
        (const void*)a16, flags, bnS[l-1], pG[l-1], pBE[l-1],
        pWT[l], pAS[l], pAD[l], h16, als, ald, N_NODES);
    k_attn<4, 32, 0><<<attnBlocks, 256, 0, stream>>>(h16, als, ald, offs, ssrc, pB[l],
        a16, bnS[l], nullptr, nullptr, nullptr, nullptr, N_NODES);
  }
  // final layer (1 head, 64 ch) + fused pool
  k_gemm<64, false><<<gemmBlocks, 256, 0, stream>>>(
      (const void*)a16, flags, bnS[2], pG[2], pBE[2],
      pWT[3], pAS[3], pAD[3], h16, als, ald, N_NODES);
  k_attn<1, 64, 1><<<attnBlocks, 256, 0, stream>>>(h16, als, ald, offs, ssrc, pB[3],
      nullptr, nullptr, bids, flags, psum, gcnt, N_NODES);

  k_pool_fin<<<16, 256, 0, stream>>>(psum, gcnt, (float*)d_out);
}

// Round 13
// 419.699 us; speedup vs baseline: 1.5081x; 1.0077x over previous
//
#include <hip/hip_runtime.h>

#define DEVINL __device__ __forceinline__

constexpr int N_NODES = 50000;
constexpr int E_EDGES = 800000;
constexpr int HD      = 128;
constexpr int NG      = 64;
constexpr int OUTC    = 64;
constexpr int NPAR    = 22;
constexpr int PAR_TOTAL = 3*(16384+3*128) + (8192+3*64) + 6*128;  // 59456
constexpr int WT_TOTAL = 3*128*128 + 64*128;     // 57344 fp16
constexpr int NB      = (N_NODES + 1023) / 1024; // 49 buckets
constexpr int EBC     = 2048;
constexpr int NBLKC   = (E_EDGES + EBC - 1) / EBC; // 391
constexpr int BNSLOTS = 16;
constexpr int PREP_BLOCKS = (PAR_TOTAL + WT_TOTAL + 255) / 256;  // 457 (> NBLKC)

typedef _Float16 half8_t __attribute__((ext_vector_type(8)));
typedef _Float16 half4_t __attribute__((ext_vector_type(4)));
typedef float    float4_t __attribute__((ext_vector_type(4)));

DEVINL float bf2f(unsigned short u){
  union { unsigned int i; float f; } v; v.i = ((unsigned int)u) << 16; return v.f;
}
DEVINL float lrelu(float v){ return v > 0.f ? v : 0.2f * v; }

// ---------------- prep: param cvt + W transpose + dtype sniff + edge count ----------------
struct PtrTab { const void* p[NPAR]; int off[NPAR + 1]; };

__global__ __launch_bounds__(256) void k_prep(PtrTab tab,
                       const unsigned short* __restrict__ x,
                       const int* __restrict__ ei, int* __restrict__ flags,
                       float* __restrict__ dst,
                       const void* __restrict__ W0, const void* __restrict__ W1,
                       const void* __restrict__ W2, const void* __restrict__ W3,
                       _Float16* __restrict__ wt16, int* __restrict__ btot){
  __shared__ int s_f32, s_i64;
  __shared__ int cnt[NB];
  int t = threadIdx.x, blk = blockIdx.x;
  if (t == 0){ s_f32 = 0; s_i64 = 1; }
  if (t < NB) cnt[t] = 0;
  __syncthreads();
  for (int i = t; i < 2048; i += 256){
    float v = bf2f(x[i]);
    if (!(fabsf(v) < 1e4f)) s_f32 = 1;
  }
  for (int i = t; i < 512; i += 256){
    if (ei[2 * i + 1] != 0) s_i64 = 0;
  }
  __syncthreads();
  const int f = s_f32, i64 = s_i64;
  if (blk == 0 && t == 0){ flags[0] = i64; flags[1] = f; }

  // param conversion / W transpose
  int i = blk * 256 + t;
  if (i < PAR_TOTAL){
    int k = 0;
    while (tab.off[k + 1] <= i) k++;
    int j = i - tab.off[k];
    dst[i] = f ? ((const float*)tab.p[k])[j] : bf2f(((const unsigned short*)tab.p[k])[j]);
  } else {
    int w = i - PAR_TOTAL;
    if (w < WT_TOTAL){
      const void* W; int base, Mt;
      if (w < 49152){ int l = w >> 14; base = w & 16383; Mt = 128; W = (l == 0) ? W0 : (l == 1 ? W1 : W2); }
      else { base = w - 49152; Mt = 64; W = W3; }
      int nn = base >> 7, k = base & 127;
      float val = f ? ((const float*)W)[(size_t)k * Mt + nn]
                    : bf2f(((const unsigned short*)W)[(size_t)k * Mt + nn]);
      wt16[w] = (_Float16)val;
    }
  }

  // edge-count histogram (blocks [0, NBLKC))
  if (blk < NBLKC){
    int e0 = blk * EBC;
    #pragma unroll
    for (int j = 0; j < EBC / 256; j++){
      int e = e0 + t + j * 256;
      if (e < E_EDGES){
        int d = ei[(size_t)(E_EDGES + e) << i64];
        atomicAdd(&cnt[d >> 10], 1);
      }
    }
    __syncthreads();
    if (t < NB && cnt[t] > 0) atomicAdd(&btot[t], cnt[t]);
  }
}

// ---------------- CSR: bin+scatter (local prefix from btot; zero-init curg) ----------------
__global__ __launch_bounds__(256) void k_binscatter(const int* __restrict__ ei,
                      const int* __restrict__ flags, const int* __restrict__ btot,
                      int* __restrict__ curg, unsigned int* __restrict__ ebuf2){
  __shared__ int cnt[NB];
  __shared__ int cur[NB];
  __shared__ int cb[NB];
  int t = threadIdx.x, blk = blockIdx.x;
  if (t < NB) cnt[t] = 0;
  __syncthreads();
  int f = flags[0];
  int e0 = blk * EBC;
  unsigned int my[EBC / 256];
  #pragma unroll
  for (int j = 0; j < EBC / 256; j++){
    int e = e0 + t + j * 256;
    my[j] = 0xFFFFFFFFu;
    if (e < E_EDGES){
      int s = ei[(size_t)e << f];
      int d = ei[(size_t)(E_EDGES + e) << f];
      my[j] = (unsigned int)s | ((unsigned int)d << 16);
      atomicAdd(&cnt[d >> 10], 1);
    }
  }
  __syncthreads();
  if (t == 0){
    int run = 0;
    for (int b = 0; b < NB; b++){ cb[b] = run; run += btot[b]; }
  }
  __syncthreads();
  if (t < NB && cnt[t] > 0) cur[t] = cb[t] + atomicAdd(&curg[t], cnt[t]);
  __syncthreads();
  #pragma unroll
  for (int j = 0; j < EBC / 256; j++){
    unsigned int pk = my[j];
    if (pk != 0xFFFFFFFFu){
      int p = atomicAdd(&cur[pk >> 26], 1);
      ebuf2[p] = pk;
    }
  }
}

// ---------------- CSR: per-bucket hist -> scan -> offs, scatter ssrc ----------------
__global__ __launch_bounds__(256) void k_csrD(const unsigned int* __restrict__ ebuf2,
                      const int* __restrict__ btot, int* __restrict__ offs,
                      int* __restrict__ ssrc, int n){
  __shared__ int hist[1024];
  __shared__ int wsum[256];
  __shared__ int cb[NB + 1];
  int t = threadIdx.x, b = blockIdx.x;
  int nbase = b << 10;
  if (t == 0){
    int run = 0;
    for (int bb = 0; bb < NB; bb++){ cb[bb] = run; run += btot[bb]; }
    cb[NB] = run;
  }
  for (int i = t; i < 1024; i += 256) hist[i] = 0;
  __syncthreads();
  int s0 = cb[b], s1 = cb[b + 1];
  for (int i = s0 + t; i < s1; i += 256){
    unsigned int pk = ebuf2[i];
    atomicAdd(&hist[(int)(pk >> 16) - nbase], 1);
  }
  __syncthreads();
  int base4 = t * 4;
  int v0 = hist[base4], v1 = hist[base4 + 1], v2 = hist[base4 + 2], v3 = hist[base4 + 3];
  int s = v0 + v1 + v2 + v3;
  wsum[t] = s; __syncthreads();
  for (int off = 1; off < 256; off <<= 1){
    int x2 = (t >= off) ? wsum[t - off] : 0;
    __syncthreads();
    wsum[t] += x2;
    __syncthreads();
  }
  int run = s0 + wsum[t] - s;
  int node = nbase + base4;
  if (node < n) offs[node] = run;  hist[base4] = run;  run += v0;
  if (node + 1 < n) offs[node + 1] = run;  hist[base4 + 1] = run;  run += v1;
  if (node + 2 < n) offs[node + 2] = run;  hist[base4 + 2] = run;  run += v2;
  if (node + 3 < n) offs[node + 3] = run;  hist[base4 + 3] = run;
  if (b == NB - 1 && t == 255) offs[n] = s1;
  __syncthreads();
  for (int i = s0 + t; i < s1; i += 256){
    unsigned int pk = ebuf2[i];
    int p = atomicAdd(&hist[(int)(pk >> 16) - nbase], 1);
    ssrc[p] = (int)(pk & 0xFFFFu);
  }
}

// ---------------- fused MFMA GEMM ----------------
template<int MT, bool FIRST>
__global__ __launch_bounds__(256) void k_gemm(
    const void* __restrict__ Ain, const int* __restrict__ flags,
    const float* __restrict__ bnslots,
    const float* __restrict__ g, const float* __restrict__ be,
    const _Float16* __restrict__ Wt16,
    const float* __restrict__ a_s, const float* __restrict__ a_d,
    _Float16* __restrict__ h16, float* __restrict__ als, float* __restrict__ ald,
    int n){
  __shared__ _Float16 AhL[64 * 136];
  __shared__ _Float16 WtL[MT * 72];
  __shared__ float scale[128], shift[128];
  const int t = threadIdx.x;
  const int rowBase = blockIdx.x * 64;
  if (!FIRST){
    if (t < 128){
      float s = 0.f, q = 0.f;
      #pragma unroll
      for (int sl = 0; sl < BNSLOTS; sl++){
        s += bnslots[sl * 256 + t];
        q += bnslots[sl * 256 + 128 + t];
      }
      float inv_n = 1.f / (float)n;
      float mu = s * inv_n;
      float var = q * inv_n - mu * mu;
      float sc = g[t] * rsqrtf(var + 1e-5f);
      scale[t] = sc; shift[t] = be[t] - mu * sc;
    }
    __syncthreads();
  }
  for (int f = t; f < 64 * 16; f += 256){
    int r = f >> 4, c8 = (f & 15) << 3;
    int row = rowBase + r;
    float v[8];
    if (row < n){
      if (FIRST){
        if (flags[1]){
          float4 x0 = *(const float4*)((const float*)Ain + (size_t)row * 128 + c8);
          float4 x1 = *(const float4*)((const float*)Ain + (size_t)row * 128 + c8 + 4);
          v[0]=x0.x; v[1]=x0.y; v[2]=x0.z; v[3]=x0.w;
          v[4]=x1.x; v[5]=x1.y; v[6]=x1.z; v[7]=x1.w;
        } else {
          const unsigned short* xp = (const unsigned short*)Ain + (size_t)row * 128 + c8;
          ushort4 u0 = *(const ushort4*)xp; ushort4 u1 = *(const ushort4*)(xp + 4);
          v[0]=bf2f(u0.x); v[1]=bf2f(u0.y); v[2]=bf2f(u0.z); v[3]=bf2f(u0.w);
          v[4]=bf2f(u1.x); v[5]=bf2f(u1.y); v[6]=bf2f(u1.z); v[7]=bf2f(u1.w);
        }
      } else {
        half8_t a8 = *(const half8_t*)((const _Float16*)Ain + (size_t)row * 128 + c8);
        #pragma unroll
        for (int j = 0; j < 8; j++){
          float xv = (float)a8[j] * scale[c8 + j] + shift[c8 + j];
          v[j] = xv > 0.f ? xv : (__expf(xv) - 1.f);
        }
      }
    } else {
      #pragma unroll
      for (int j = 0; j < 8; j++) v[j] = 0.f;
    }
    half8_t h;
    #pragma unroll
    for (int j = 0; j < 8; j++) h[j] = (_Float16)v[j];
    *(half8_t*)&AhL[r * 136 + c8] = h;
  }
  const int lane = t & 63;
  const int m = lane & 15, quad = lane >> 4;
  const int band = (t >> 6) * 16;
  float4_t acc[MT / 16];
  #pragma unroll
  for (int ct = 0; ct < MT / 16; ct++) acc[ct] = (float4_t){0.f, 0.f, 0.f, 0.f};
  #pragma unroll
  for (int kh = 0; kh < 2; kh++){
    __syncthreads();
    for (int f = t; f < MT * 8; f += 256){
      int nn = f >> 3, c8 = (f & 7) << 3;
      *(half8_t*)&WtL[nn * 72 + c8] = *(const half8_t*)&Wt16[nn * 128 + kh * 64 + c8];
    }
    __syncthreads();
    half8_t a0 = *(half8_t*)&AhL[(band + m) * 136 + kh * 64 + quad * 8];
    half8_t a1 = *(half8_t*)&AhL[(band + m) * 136 + kh * 64 + 32 + quad * 8];
    #pragma unroll
    for (int ct = 0; ct < MT / 16; ct++){
      half8_t b0 = *(half8_t*)&WtL[(ct * 16 + m) * 72 + quad * 8];
      half8_t b1 = *(half8_t*)&WtL[(ct * 16 + m) * 72 + 32 + quad * 8];
      acc[ct] = __builtin_amdgcn_mfma_f32_16x16x32_f16(a0, b0, acc[ct], 0, 0, 0);
      acc[ct] = __builtin_amdgcn_mfma_f32_16x16x32_f16(a1, b1, acc[ct], 0, 0, 0);
    }
  }
  __syncthreads();
  #pragma unroll
  for (int ct = 0; ct < MT / 16; ct++)
    #pragma unroll
    for (int rg = 0; rg < 4; rg++)
      AhL[(band + quad * 4 + rg) * 136 + ct * 16 + m] = (_Float16)acc[ct][rg];
  __syncthreads();
  int r = t >> 2, q = t & 3;
  int row = rowBase + r;
  if (MT == 128){
    if (row < n){
      half8_t h0 = *(half8_t*)&AhL[r * 136 + q * 32];
      half8_t h1 = *(half8_t*)&AhL[r * 136 + q * 32 + 8];
      half8_t h2 = *(half8_t*)&AhL[r * 136 + q * 32 + 16];
      half8_t h3 = *(half8_t*)&AhL[r * 136 + q * 32 + 24];
      float pas = 0.f, pad = 0.f;
      #pragma unroll
      for (int j = 0; j < 8; j++){
        pas += (float)h0[j] * a_s[q * 32 + j]      + (float)h1[j] * a_s[q * 32 + 8 + j]
             + (float)h2[j] * a_s[q * 32 + 16 + j] + (float)h3[j] * a_s[q * 32 + 24 + j];
        pad += (float)h0[j] * a_d[q * 32 + j]      + (float)h1[j] * a_d[q * 32 + 8 + j]
             + (float)h2[j] * a_d[q * 32 + 16 + j] + (float)h3[j] * a_d[q * 32 + 24 + j];
      }
      als[(size_t)row * 4 + q] = pas;
      ald[(size_t)row * 4 + q] = pad;
      _Float16* hp = h16 + (size_t)row * 128 + q * 32;
      *(half8_t*)hp = h0; *(half8_t*)(hp + 8) = h1;
      *(half8_t*)(hp + 16) = h2; *(half8_t*)(hp + 24) = h3;
    }
  } else {
    half8_t h0 = *(half8_t*)&AhL[r * 136 + q * 16];
    half8_t h1 = *(half8_t*)&AhL[r * 136 + q * 16 + 8];
    float pas = 0.f, pad = 0.f;
    #pragma unroll
    for (int j = 0; j < 8; j++){
      pas += (float)h0[j] * a_s[q * 16 + j] + (float)h1[j] * a_s[q * 16 + 8 + j];
      pad += (float)h0[j] * a_d[q * 16 + j] + (float)h1[j] * a_d[q * 16 + 8 + j];
    }
    pas += __shfl_xor(pas, 1); pas += __shfl_xor(pas, 2);
    pad += __shfl_xor(pad, 1); pad += __shfl_xor(pad, 2);
    if (row < n){
      _Float16* hp = h16 + (size_t)row * 64 + q * 16;
      *(half8_t*)hp = h0; *(half8_t*)(hp + 8) = h1;
      if (q == 0){ als[row] = pas; ald[row] = pad; }
    }
  }
}

// ---------------- per-node GAT attention + aggregation (fused epilogues) ----------------
// 16-lane group per node; per-lane ssum; 8-wide gather unroll.
// MODE 0: fp16 out + BN partial sums into 16 slots. MODE 1: fused mean-pool.
template<int H, int C, int MODE>
__global__ __launch_bounds__(256) void k_attn(const _Float16* __restrict__ h16,
                      const float* __restrict__ als, const float* __restrict__ ald,
                      const int* __restrict__ offs, const int* __restrict__ ssrc,
                      const float* __restrict__ bias,
                      _Float16* __restrict__ a16out, float* __restrict__ bnout,
                      const int* __restrict__ bids, const int* __restrict__ flags,
                      float* __restrict__ psum, int* __restrict__ gcnt, int n){
  constexpr int HC = H * C;
  constexpr int CPL = HC / 16;                 // 8 (4x32) or 4 (1x64)
  int t = threadIdx.x;
  int nib  = t >> 4;
  int node = blockIdx.x * 16 + nib;
  int sub  = t & 15;
  int c0   = sub * CPL;
  int head = c0 / C;

  float ald_h = ald[(size_t)node * H + head];
  float acc[CPL];
  float ssum;
  {
    float w = __expf(lrelu(als[(size_t)node * H + head] + ald_h));
    ssum = w;
    const _Float16* hp = h16 + (size_t)node * HC + c0;
    #pragma unroll
    for (int i = 0; i < CPL; i++) acc[i] = w * (float)hp[i];
  }
  int beg = offs[node];
  int deg = offs[node + 1] - beg;
  int j = 0;
  for (; j + 8 <= deg; j += 8){
    int ss[8]; float al[8]; float w[8];
    #pragma unroll
    for (int u = 0; u < 8; u++) ss[u] = ssrc[beg + j + u];
    #pragma unroll
    for (int u = 0; u < 8; u++) al[u] = als[(size_t)ss[u] * H + head];
    if constexpr (CPL == 8){
      half8_t v[8];
      #pragma unroll
      for (int u = 0; u < 8; u++) v[u] = *(const half8_t*)(h16 + (size_t)ss[u] * HC + c0);
      #pragma unroll
      for (int u = 0; u < 8; u++){ w[u] = __expf(lrelu(al[u] + ald_h)); ssum += w[u]; }
      #pragma unroll
      for (int i = 0; i < 8; i++){
        float a = 0.f;
        #pragma unroll
        for (int u = 0; u < 8; u++) a += w[u] * (float)v[u][i];
        acc[i] += a;
      }
    } else {
      half4_t v[8];
      #pragma unroll
      for (int u = 0; u < 8; u++) v[u] = *(const half4_t*)(h16 + (size_t)ss[u] * HC + c0);
      #pragma unroll
      for (int u = 0; u < 8; u++){ w[u] = __expf(lrelu(al[u] + ald_h)); ssum += w[u]; }
      #pragma unroll
      for (int i = 0; i < 4; i++){
        float a = 0.f;
        #pragma unroll
        for (int u = 0; u < 8; u++) a += w[u] * (float)v[u][i];
        acc[i] += a;
      }
    }
  }
  for (; j + 4 <= deg; j += 4){
    int s0 = ssrc[beg + j], s1 = ssrc[beg + j + 1];
    int s2 = ssrc[beg + j + 2], s3 = ssrc[beg + j + 3];
    float al0 = als[(size_t)s0 * H + head], al1 = als[(size_t)s1 * H + head];
    float al2 = als[(size_t)s2 * H + head], al3 = als[(size_t)s3 * H + head];
    float w0 = __expf(lrelu(al0 + ald_h)), w1 = __expf(lrelu(al1 + ald_h));
    float w2 = __expf(lrelu(al2 + ald_h)), w3 = __expf(lrelu(al3 + ald_h));
    ssum += (w0 + w1) + (w2 + w3);
    if constexpr (CPL == 8){
      half8_t v0 = *(const half8_t*)(h16 + (size_t)s0 * HC + c0);
      half8_t v1 = *(const half8_t*)(h16 + (size_t)s1 * HC + c0);
      half8_t v2 = *(const half8_t*)(h16 + (size_t)s2 * HC + c0);
      half8_t v3 = *(const half8_t*)(h16 + (size_t)s3 * HC + c0);
      #pragma unroll
      for (int i = 0; i < 8; i++)
        acc[i] += w0 * (float)v0[i] + w1 * (float)v1[i]
                + w2 * (float)v2[i] + w3 * (float)v3[i];
    } else {
      half4_t v0 = *(const half4_t*)(h16 + (size_t)s0 * HC + c0);
      half4_t v1 = *(const half4_t*)(h16 + (size_t)s1 * HC + c0);
      half4_t v2 = *(const half4_t*)(h16 + (size_t)s2 * HC + c0);
      half4_t v3 = *(const half4_t*)(h16 + (size_t)s3 * HC + c0);
      #pragma unroll
      for (int i = 0; i < 4; i++)
        acc[i] += w0 * (float)v0[i] + w1 * (float)v1[i]
                + w2 * (float)v2[i] + w3 * (float)v3[i];
    }
  }
  for (; j < deg; j++){
    int s0 = ssrc[beg + j];
    float w0 = __expf(lrelu(als[(size_t)s0 * H + head] + ald_h));
    ssum += w0;
    const _Float16* hp = h16 + (size_t)s0 * HC + c0;
    #pragma unroll
    for (int i = 0; i < CPL; i++) acc[i] += w0 * (float)hp[i];
  }
  float inv_s = 1.f / ssum;
  float v[CPL];
  #pragma unroll
  for (int i = 0; i < CPL; i++) v[i] = acc[i] * inv_s + bias[c0 + i];

  if constexpr (MODE == 0){
    _Float16* op = a16out + (size_t)node * HC + c0;
    half8_t o;
    #pragma unroll
    for (int i = 0; i < CPL; i++) o[i] = (_Float16)v[i];
    *(half8_t*)op = o;
    __shared__ float red[16][132];
    *(float4*)&red[nib][c0]     = make_float4(v[0], v[1], v[2], v[3]);
    *(float4*)&red[nib][c0 + 4] = make_float4(v[4], v[5], v[6], v[7]);
    __syncthreads();
    if (t < 128){
      float s = 0.f, q = 0.f;
      #pragma unroll
      for (int i = 0; i < 16; i++){ float x = red[i][t]; s += x; q += x * x; }
      int slot = blockIdx.x & (BNSLOTS - 1);
      atomicAdd(&bnout[slot * 256 + t], s);
      atomicAdd(&bnout[slot * 256 + 128 + t], q);
    }
  } else {
    __shared__ float pacc[2][64];
    __shared__ int pcnt[2];
    int f = flags[0];
    if (t < 128) pacc[t >> 6][t & 63] = 0.f;
    if (t < 2) pcnt[t] = 0;
    __syncthreads();
    int g  = (int)bids[(size_t)node << f];
    int g0 = (int)bids[(size_t)(blockIdx.x * 16) << f];
    int g1 = (int)bids[(size_t)(blockIdx.x * 16 + 15) << f];
    if (g1 - g0 <= 1){
      int gl = g - g0;
      #pragma unroll
      for (int i = 0; i < 4; i++) atomicAdd(&pacc[gl][c0 + i], v[i]);
      if (sub == 0) atomicAdd(&pcnt[gl], 1);
      __syncthreads();
      if (t < 128){
        int gl2 = t >> 6;
        if (pcnt[gl2] > 0) atomicAdd(&psum[(g0 + gl2) * 64 + (t & 63)], pacc[gl2][t & 63]);
      }
      if (t < 2 && pcnt[t] > 0) atomicAdd(&gcnt[g0 + t], pcnt[t]);
    } else {
      #pragma unroll
      for (int i = 0; i < 4; i++) atomicAdd(&psum[g * 64 + c0 + i], v[i]);
      if (sub == 0) atomicAdd(&gcnt[g], 1);
      __syncthreads();
    }
  }
}

__global__ void k_pool_fin(const float* __restrict__ psum, const int* __restrict__ gcnt,
                           float* __restrict__ out){
  int i = blockIdx.x * 256 + threadIdx.x;
  if (i >= NG * OUTC) return;
  int cnt = gcnt[i >> 6];
  out[i] = psum[i] / (float)(cnt > 1 ? cnt : 1);
}

extern "C" void kernel_launch(void* const* d_in, const int* in_sizes, int n_in,
                              void* d_out, int out_size, void* d_ws, size_t ws_size,
                              hipStream_t stream){
  const unsigned short* x    = (const unsigned short*)d_in[0];
  const int*            ei   = (const int*)d_in[1];
  const int*            bids = (const int*)d_in[2];

  char* p = (char*)d_ws;
  auto carve = [&](size_t bytes) -> void* {
    void* r = (void*)p; p += (bytes + 255) & ~size_t(255); return r;
  };
  _Float16* a16    = (_Float16*)carve((size_t)N_NODES * HD * 2);
  _Float16* h16    = (_Float16*)carve((size_t)N_NODES * HD * 2);
  float*    par    = (float*)carve((size_t)PAR_TOTAL * 4);
  _Float16* wt16   = (_Float16*)carve((size_t)WT_TOTAL * 2);
  float*    als    = (float*)carve((size_t)N_NODES * 4 * 4);
  float*    ald    = (float*)carve((size_t)N_NODES * 4 * 4);
  int*      offs   = (int*)carve((size_t)(N_NODES + 1) * 4);
  int*      ssrc   = (int*)carve((size_t)E_EDGES * 4);
  unsigned int* ebuf2 = (unsigned int*)carve((size_t)E_EDGES * 4);
  int*      flags  = (int*)carve(256);
  // contiguous zero-region (single memset)
  char*     zbeg   = p;
  int*      btot   = (int*)carve(256);
  int*      curg   = (int*)carve(256);
  float*    bnbuf  = (float*)carve((size_t)3 * BNSLOTS * 256 * 4);  // 48 KB
  float*    psum   = (float*)carve(NG * OUTC * 4);
  int*      gcnt   = (int*)carve(256);
  size_t    zlen   = (size_t)(p - zbeg);

  // param table (dict order indices 3..24)
  PtrTab tab;
  int sizes[NPAR];
  for (int l = 0; l < 4; l++){
    int base = 3 + 4 * l;
    tab.p[4 * l + 0] = d_in[base + 0]; sizes[4 * l + 0] = (l < 3) ? 16384 : 8192;
    tab.p[4 * l + 1] = d_in[base + 1]; sizes[4 * l + 1] = (l < 3) ? 128 : 64;
    tab.p[4 * l + 2] = d_in[base + 2]; sizes[4 * l + 2] = (l < 3) ? 128 : 64;
    tab.p[4 * l + 3] = d_in[base + 3]; sizes[4 * l + 3] = (l < 3) ? 128 : 64;
  }
  for (int l = 0; l < 3; l++){
    tab.p[16 + 2 * l]     = d_in[19 + 2 * l];     sizes[16 + 2 * l] = 128;
    tab.p[16 + 2 * l + 1] = d_in[19 + 2 * l + 1]; sizes[16 + 2 * l + 1] = 128;
  }
  tab.off[0] = 0;
  for (int k = 0; k < NPAR; k++) tab.off[k + 1] = tab.off[k] + sizes[k];
  const float* pAS[4], *pAD[4], *pB[4], *pG[3], *pBE[3];
  for (int l = 0; l < 4; l++){
    pAS[l] = par + tab.off[4 * l + 1];
    pAD[l] = par + tab.off[4 * l + 2];
    pB[l]  = par + tab.off[4 * l + 3];
  }
  for (int l = 0; l < 3; l++){
    pG[l]  = par + tab.off[16 + 2 * l];
    pBE[l] = par + tab.off[16 + 2 * l + 1];
  }
  const _Float16* pWT[4] = { wt16, wt16 + 16384, wt16 + 32768, wt16 + 49152 };
  float* bnS[3];
  for (int l = 0; l < 3; l++) bnS[l] = bnbuf + (size_t)l * BNSLOTS * 256;

  hipMemsetAsync(zbeg, 0, zlen, stream);

  // prep (self-sniffing dtype flags) + edge-count histogram (merged)
  k_prep<<<PREP_BLOCKS, 256, 0, stream>>>(
      tab, x, ei, flags, par, d_in[3], d_in[7], d_in[11], d_in[15], wt16, btot);

  // CSR build
  k_binscatter<<<NBLKC, 256, 0, stream>>>(ei, flags, btot, curg, ebuf2);
  k_csrD<<<NB, 256, 0, stream>>>(ebuf2, btot, offs, ssrc, N_NODES);

  int gemmBlocks = (N_NODES + 63) / 64;
  int attnBlocks = N_NODES / 16;   // 3125, exact

  // layer 0
  k_gemm<128, true><<<gemmBlocks, 256, 0, stream>>>(
      (const void*)x, flags, nullptr, nullptr, nullptr,
      pWT[0], pAS[0], pAD[0], h16, als, ald, N_NODES);
  k_attn<4, 32, 0><<<attnBlocks, 256, 0, stream>>>(h16, als, ald, offs, ssrc, pB[0],
      a16, bnS[0], nullptr, nullptr, nullptr, nullptr, N_NODES);
  // layers 1,2
  for (int l = 1; l < 3; l++){
    k_gemm<128, false><<<gemmBlocks, 256, 0, stream>>>(
        (const void*)a16, flags, bnS[l-1], pG[l-1], pBE[l-1],
        pWT[l], pAS[l], pAD[l], h16, als, ald, N_NODES);
    k_attn<4, 32, 0><<<attnBlocks, 256, 0, stream>>>(h16, als, ald, offs, ssrc, pB[l],
        a16, bnS[l], nullptr, nullptr, nullptr, nullptr, N_NODES);
  }
  // final layer (1 head, 64 ch) + fused pool
  k_gemm<64, false><<<gemmBlocks, 256, 0, stream>>>(
      (const void*)a16, flags, bnS[2], pG[2], pBE[2],
      pWT[3], pAS[3], pAD[3], h16, als, ald, N_NODES);
  k_attn<1, 64, 1><<<attnBlocks, 256, 0, stream>>>(h16, als, ald, offs, ssrc, pB[3],
      nullptr, nullptr, bids, flags, psum, gcnt, N_NODES);

  k_pool_fin<<<16, 256, 0, stream>>>(psum, gcnt, (float*)d_out);
}